// Round 1
// baseline (82.939 us; speedup 1.0000x reference)
//
#include <hip/hip_runtime.h>
#include <math.h>

#define BATCH 8192
#define DIM 12
#define NCB 4
#define NBINS 4096

// ws layout (floats):
//  [0 .. 16384)        : hist  (4 codebooks x 4096 bins), zeroed each call
//  [16384]             : commit_sum
//  [16385]             : per-sample-entropy sum
//  [16416 .. +48*8192) : p buffer, layout p[(cb*12+d)*8192 + b]
#define HIST_OFF 0
#define CSUM_OFF 16384
#define HSUM_OFF 16385
#define PBUF_OFF 16416

__global__ __launch_bounds__(256)
void lfq_sample_kernel(const float* __restrict__ x, float* __restrict__ out,
                       float* __restrict__ ws) {
    int b = blockIdx.x * 256 + threadIdx.x;
    const float4* xv = reinterpret_cast<const float4*>(x + b * 12);
    float4 v0 = xv[0], v1 = xv[1], v2 = xv[2];
    float r[12] = {v0.x, v0.y, v0.z, v0.w, v1.x, v1.y, v1.z, v1.w,
                   v2.x, v2.y, v2.z, v2.w};
    float xh[12];
#pragma unroll
    for (int d = 0; d < 12; ++d) xh[d] = 0.f;

    float csum = 0.f, hsum = 0.f;
    float* pbuf = ws + PBUF_OFF;
    const float scales[4] = {1.0f, 0.5f, 0.25f, 0.125f};

#pragma unroll
    for (int cb = 0; cb < 4; ++cb) {
        float scale = scales[cb];
#pragma unroll
        for (int d = 0; d < 12; ++d) {
            float rd = r[d];
            float q = (rd > 0.f) ? scale : -scale;
            float diff = rd - q;
            csum += diff * diff;
            // a = 2*scale*r ; binary-softmax entropy H2 = lse - a*tanh(a)
            float a = 2.f * scale * rd;
            float m = fabsf(a);
            float u = __expf(-2.f * m);           // in (0,1]
            float lse = m + log1pf(u);            // log(e^a + e^-a) = log(2cosh a)
            float th = (1.f - u) / (1.f + u);     // tanh(m)
            hsum += lse - m * th;
            // p(s=+1) = sigmoid(2a)
            float pp = (a >= 0.f) ? 1.f / (1.f + u) : u / (1.f + u);
            pbuf[(cb * 12 + d) * BATCH + b] = pp;
            xh[d] += q;
            r[d] = rd - q;
        }
    }

    float4* ov = reinterpret_cast<float4*>(out + b * 12);
    ov[0] = make_float4(xh[0], xh[1], xh[2], xh[3]);
    ov[1] = make_float4(xh[4], xh[5], xh[6], xh[7]);
    ov[2] = make_float4(xh[8], xh[9], xh[10], xh[11]);

#pragma unroll
    for (int off = 32; off; off >>= 1) {
        csum += __shfl_down(csum, off);
        hsum += __shfl_down(hsum, off);
    }
    if ((threadIdx.x & 63) == 0) {
        atomicAdd(ws + CSUM_OFF, csum);
        atomicAdd(ws + HSUM_OFF, hsum);
    }
}

// histogram kernel: 256 blocks x 256 threads, 32 samples/block (2 rounds of 16)
#define SROUND 16
#define TSTR 516  // floats; *4B = 2064, multiple of 16 -> float4-aligned rows

__global__ __launch_bounds__(256)
void lfq_hist_kernel(const float* __restrict__ pbuf, float* __restrict__ hist) {
    __shared__ float P[SROUND * 49];                 // p values, padded stride 49
    __shared__ __align__(16) float T[SROUND * TSTR]; // per-sample L/H tables

    int t = threadIdx.x;
    int w = t >> 6;      // wave id 0..3
    int lane = t & 63;

    float acc[4][16];
#pragma unroll
    for (int cb = 0; cb < 4; ++cb)
#pragma unroll
        for (int i = 0; i < 16; ++i) acc[cb][i] = 0.f;

    int b0 = blockIdx.x * 32;

    for (int round = 0; round < 2; ++round) {
        int sb = b0 + round * SROUND;
        __syncthreads();  // protect LDS from previous round's readers
        // load 16 samples x 48 p-values, coalesced over b
        for (int idx = t; idx < SROUND * 48; idx += 256) {
            int s = idx & 15;
            int cd = idx >> 4;
            P[s * 49 + cd] = pbuf[cd * BATCH + sb + s];
        }
        __syncthreads();
        // build tables: 16 samples x (4cb x 128 entries) = 8192 entries
        for (int i = 0; i < 32; ++i) {
            int e = t + 256 * i;
            int s = e >> 9;       // uniform per wave
            int cj = e & 511;     // consecutive per lane -> conflict-free store
            int cb = cj >> 7;     // uniform per wave
            int j = cj & 127;
            int jj = j & 63;
            int dbase = (j >> 6) * 6;  // 0 for L-table, 6 for H-table
            const float* pp = &P[s * 49 + cb * 12 + dbase];
            float v = 1.f;
#pragma unroll
            for (int d = 0; d < 6; ++d) {
                float p = pp[d];                     // broadcast read
                v *= ((jj >> d) & 1) ? p : (1.f - p);
            }
            T[s * TSTR + cj] = v;
        }
        __syncthreads();
        // accumulate: thread owns bins k = (16*w + i)*64 + lane
        for (int s = 0; s < SROUND; ++s) {
#pragma unroll
            for (int cb = 0; cb < 4; ++cb) {
                const float* Ts = &T[s * TSTR + cb * 128];
                float Lv = Ts[lane];  // lane-consecutive -> conflict-free
                const float4* Hv =
                    reinterpret_cast<const float4*>(Ts + 64 + 16 * w);
#pragma unroll
                for (int i4 = 0; i4 < 4; ++i4) {
                    float4 h = Hv[i4];  // wave-uniform -> broadcast
                    acc[cb][4 * i4 + 0] += h.x * Lv;
                    acc[cb][4 * i4 + 1] += h.y * Lv;
                    acc[cb][4 * i4 + 2] += h.z * Lv;
                    acc[cb][4 * i4 + 3] += h.w * Lv;
                }
            }
        }
    }
#pragma unroll
    for (int cb = 0; cb < 4; ++cb)
#pragma unroll
        for (int i = 0; i < 16; ++i)
            atomicAdd(&hist[cb * NBINS + (16 * w + i) * 64 + lane], acc[cb][i]);
}

__global__ __launch_bounds__(256)
void lfq_final_kernel(const float* __restrict__ ws, float* __restrict__ out) {
    int t = threadIdx.x;
    float ce = 0.f;
    for (int idx = t; idx < NCB * NBINS; idx += 256) {
        float avgp = ws[HIST_OFF + idx] * (1.0f / 8192.0f);
        ce += avgp * logf(avgp + 1e-9f);
    }
#pragma unroll
    for (int off = 32; off; off >>= 1) ce += __shfl_down(ce, off);
    __shared__ float red[4];
    if ((t & 63) == 0) red[t >> 6] = ce;
    __syncthreads();
    if (t == 0) {
        float cesum = red[0] + red[1] + red[2] + red[3];
        float codebook_entropy = -cesum;
        float commit = ws[CSUM_OFF] * (1.0f / (8192.0f * 12.0f));
        float pse = ws[HSUM_OFF] * (1.0f / 8192.0f);
        float entropy_loss = pse - codebook_entropy;
        float loss = 0.1f * commit + 0.1f * commit + entropy_loss;
        out[BATCH * DIM + 0] = loss;
        out[BATCH * DIM + 1] = commit;
        out[BATCH * DIM + 2] = commit;  // codebook loss == commit in fwd
        out[BATCH * DIM + 3] = entropy_loss;
    }
}

extern "C" void kernel_launch(void* const* d_in, const int* in_sizes, int n_in,
                              void* d_out, int out_size, void* d_ws,
                              size_t ws_size, hipStream_t stream) {
    const float* x = (const float*)d_in[0];
    float* out = (float*)d_out;
    float* ws = (float*)d_ws;

    // zero hist + scalar accumulators (poisoned 0xAA otherwise)
    hipMemsetAsync(ws, 0, (16384 + 32) * sizeof(float), stream);

    hipLaunchKernelGGL(lfq_sample_kernel, dim3(BATCH / 256), dim3(256), 0,
                       stream, x, out, ws);
    hipLaunchKernelGGL(lfq_hist_kernel, dim3(BATCH / 32), dim3(256), 0, stream,
                       ws + PBUF_OFF, ws + HIST_OFF);
    hipLaunchKernelGGL(lfq_final_kernel, dim3(1), dim3(256), 0, stream, ws,
                       out);
}

// Round 2
// 58.807 us; speedup vs baseline: 1.4104x; 1.4104x over previous
//
#include <hip/hip_runtime.h>
#include <math.h>

#define BATCH 8192
#define DIM 12
#define NCB 4
#define NBINS 4096
#define HBINS (NCB * NBINS)  // 16384

// ws layout (floats) — every slot fully written each call, no zero-init needed:
//  [0 .. 393216)            : p buffer, p[(cb*12+d)*8192 + b]
//  [393216 .. +256*16384)   : per-block partial hists  partial[blk][16384]
//  [4587520 .. +128)        : commit partial sums (32 blocks x 4 waves)
//  [4587648 .. +128)        : per-sample-entropy partials
//  [4587776 .. +256)        : codebook-entropy partials (64 blocks x 4 waves)
#define PBUF_OFF 0
#define PART_OFF 393216
#define CPART_OFF 4587520
#define HPART_OFF 4587648
#define CEPART_OFF 4587776

__global__ __launch_bounds__(256)
void lfq_sample_kernel(const float* __restrict__ x, float* __restrict__ out,
                       float* __restrict__ ws) {
    int b = blockIdx.x * 256 + threadIdx.x;
    const float4* xv = reinterpret_cast<const float4*>(x + b * 12);
    float4 v0 = xv[0], v1 = xv[1], v2 = xv[2];
    float r[12] = {v0.x, v0.y, v0.z, v0.w, v1.x, v1.y, v1.z, v1.w,
                   v2.x, v2.y, v2.z, v2.w};
    float xh[12];
#pragma unroll
    for (int d = 0; d < 12; ++d) xh[d] = 0.f;

    float csum = 0.f, hsum = 0.f;
    float* pbuf = ws + PBUF_OFF;
    const float scales[4] = {1.0f, 0.5f, 0.25f, 0.125f};

#pragma unroll
    for (int cb = 0; cb < 4; ++cb) {
        float scale = scales[cb];
#pragma unroll
        for (int d = 0; d < 12; ++d) {
            float rd = r[d];
            float q = (rd > 0.f) ? scale : -scale;
            float diff = rd - q;
            csum += diff * diff;
            // a = 2*scale*r ; binary-softmax entropy H2 = lse - a*tanh(a)
            float a = 2.f * scale * rd;
            float m = fabsf(a);
            float u = __expf(-2.f * m);        // in (0,1]
            float lse = m + log1pf(u);         // log(2 cosh a)
            float th = (1.f - u) / (1.f + u);  // tanh(m)
            hsum += lse - m * th;
            // p(s=+1) = sigmoid(2a)
            float pp = (a >= 0.f) ? 1.f / (1.f + u) : u / (1.f + u);
            pbuf[(cb * 12 + d) * BATCH + b] = pp;
            xh[d] += q;
            r[d] = rd - q;
        }
    }

    float4* ov = reinterpret_cast<float4*>(out + b * 12);
    ov[0] = make_float4(xh[0], xh[1], xh[2], xh[3]);
    ov[1] = make_float4(xh[4], xh[5], xh[6], xh[7]);
    ov[2] = make_float4(xh[8], xh[9], xh[10], xh[11]);

#pragma unroll
    for (int off = 32; off; off >>= 1) {
        csum += __shfl_down(csum, off);
        hsum += __shfl_down(hsum, off);
    }
    int w = threadIdx.x >> 6;
    if ((threadIdx.x & 63) == 0) {
        ws[CPART_OFF + blockIdx.x * 4 + w] = csum;
        ws[HPART_OFF + blockIdx.x * 4 + w] = hsum;
    }
}

// histogram kernel: 256 blocks x 256 threads, 32 samples/block (2 rounds of 16)
// writes a private partial hist per block — NO atomics.
#define SROUND 16
#define TSTR 516  // floats; *4B = 2064, multiple of 16 -> float4-aligned rows

__global__ __launch_bounds__(256)
void lfq_hist_kernel(const float* __restrict__ pbuf,
                     float* __restrict__ partial) {
    __shared__ float P[SROUND * 49];                  // p values, stride 49
    __shared__ __align__(16) float T[SROUND * TSTR];  // per-sample L/H tables

    int t = threadIdx.x;
    int w = t >> 6;  // wave id 0..3
    int lane = t & 63;

    float acc[4][16];
#pragma unroll
    for (int cb = 0; cb < 4; ++cb)
#pragma unroll
        for (int i = 0; i < 16; ++i) acc[cb][i] = 0.f;

    int b0 = blockIdx.x * 32;

    for (int round = 0; round < 2; ++round) {
        int sb = b0 + round * SROUND;
        __syncthreads();  // protect LDS from previous round's readers
        for (int idx = t; idx < SROUND * 48; idx += 256) {
            int s = idx & 15;
            int cd = idx >> 4;
            P[s * 49 + cd] = pbuf[cd * BATCH + sb + s];
        }
        __syncthreads();
        // build tables: 16 samples x (4cb x 128 entries) = 8192 entries
        for (int i = 0; i < 32; ++i) {
            int e = t + 256 * i;
            int s = e >> 9;
            int cj = e & 511;
            int cb = cj >> 7;
            int j = cj & 127;
            int jj = j & 63;
            int dbase = (j >> 6) * 6;  // 0 = L-table (d 0..5), 6 = H (d 6..11)
            const float* pp = &P[s * 49 + cb * 12 + dbase];
            float v = 1.f;
#pragma unroll
            for (int d = 0; d < 6; ++d) {
                float p = pp[d];
                v *= ((jj >> d) & 1) ? p : (1.f - p);
            }
            T[s * TSTR + cj] = v;
        }
        __syncthreads();
        for (int s = 0; s < SROUND; ++s) {
#pragma unroll
            for (int cb = 0; cb < 4; ++cb) {
                const float* Ts = &T[s * TSTR + cb * 128];
                float Lv = Ts[lane];
                const float4* Hv =
                    reinterpret_cast<const float4*>(Ts + 64 + 16 * w);
#pragma unroll
                for (int i4 = 0; i4 < 4; ++i4) {
                    float4 h = Hv[i4];
                    acc[cb][4 * i4 + 0] += h.x * Lv;
                    acc[cb][4 * i4 + 1] += h.y * Lv;
                    acc[cb][4 * i4 + 2] += h.z * Lv;
                    acc[cb][4 * i4 + 3] += h.w * Lv;
                }
            }
        }
    }
    float* mypart = partial + blockIdx.x * HBINS;
#pragma unroll
    for (int cb = 0; cb < 4; ++cb)
#pragma unroll
        for (int i = 0; i < 16; ++i)
            mypart[cb * NBINS + (16 * w + i) * 64 + lane] = acc[cb][i];
}

// reduce kernel: 64 blocks x 256 threads; thread owns one bin, sums 256
// block-partials (lane-consecutive bins -> coalesced), emits ce partials.
__global__ __launch_bounds__(256)
void lfq_reduce_kernel(const float* __restrict__ partial,
                       float* __restrict__ ws) {
    int bin = blockIdx.x * 256 + threadIdx.x;
    float s0 = 0.f, s1 = 0.f, s2 = 0.f, s3 = 0.f;
#pragma unroll 4
    for (int blk = 0; blk < 256; blk += 4) {
        s0 += partial[(blk + 0) * HBINS + bin];
        s1 += partial[(blk + 1) * HBINS + bin];
        s2 += partial[(blk + 2) * HBINS + bin];
        s3 += partial[(blk + 3) * HBINS + bin];
    }
    float avgp = (s0 + s1 + s2 + s3) * (1.0f / 8192.0f);
    float term = avgp * __logf(avgp + 1e-9f);
#pragma unroll
    for (int off = 32; off; off >>= 1) term += __shfl_down(term, off);
    int w = threadIdx.x >> 6;
    if ((threadIdx.x & 63) == 0)
        ws[CEPART_OFF + blockIdx.x * 4 + w] = term;
}

__global__ __launch_bounds__(256)
void lfq_final_kernel(const float* __restrict__ ws, float* __restrict__ out) {
    int t = threadIdx.x;
    float ce = ws[CEPART_OFF + t];
    float cs = (t < 128) ? ws[CPART_OFF + t] : 0.f;
    float hs = (t < 128) ? ws[HPART_OFF + t] : 0.f;
#pragma unroll
    for (int off = 32; off; off >>= 1) {
        ce += __shfl_down(ce, off);
        cs += __shfl_down(cs, off);
        hs += __shfl_down(hs, off);
    }
    __shared__ float red[3][4];
    if ((t & 63) == 0) {
        red[0][t >> 6] = ce;
        red[1][t >> 6] = cs;
        red[2][t >> 6] = hs;
    }
    __syncthreads();
    if (t == 0) {
        float cesum = red[0][0] + red[0][1] + red[0][2] + red[0][3];
        float codebook_entropy = -cesum;
        float commit =
            (red[1][0] + red[1][1] + red[1][2] + red[1][3]) *
            (1.0f / (8192.0f * 12.0f));
        float pse =
            (red[2][0] + red[2][1] + red[2][2] + red[2][3]) * (1.0f / 8192.0f);
        float entropy_loss = pse - codebook_entropy;
        float loss = 0.1f * commit + 0.1f * commit + entropy_loss;
        out[BATCH * DIM + 0] = loss;
        out[BATCH * DIM + 1] = commit;
        out[BATCH * DIM + 2] = commit;  // codebook loss == commit in fwd
        out[BATCH * DIM + 3] = entropy_loss;
    }
}

extern "C" void kernel_launch(void* const* d_in, const int* in_sizes, int n_in,
                              void* d_out, int out_size, void* d_ws,
                              size_t ws_size, hipStream_t stream) {
    const float* x = (const float*)d_in[0];
    float* out = (float*)d_out;
    float* ws = (float*)d_ws;

    hipLaunchKernelGGL(lfq_sample_kernel, dim3(BATCH / 256), dim3(256), 0,
                       stream, x, out, ws);
    hipLaunchKernelGGL(lfq_hist_kernel, dim3(BATCH / 32), dim3(256), 0, stream,
                       ws + PBUF_OFF, ws + PART_OFF);
    hipLaunchKernelGGL(lfq_reduce_kernel, dim3(HBINS / 256), dim3(256), 0,
                       stream, ws + PART_OFF, ws);
    hipLaunchKernelGGL(lfq_final_kernel, dim3(1), dim3(256), 0, stream, ws,
                       out);
}

// Round 3
// 46.638 us; speedup vs baseline: 1.7784x; 1.2609x over previous
//
#include <hip/hip_runtime.h>
#include <math.h>

#define BATCH 8192
#define NCB 4
#define NBINS 4096
#define HBINS (NCB * NBINS)  // 16384
#define NBLK 256
#define SPB 32  // samples per block

// ws float offsets — every slot written each call before use; counter is
// zeroed by K1 each call (poison-safe, deterministic).
#define PART_OFF 0                      // 256 * 16384 partial hists
#define CPART_OFF (NBLK * HBINS)        // 4194304: 256 commit partials
#define HPART_OFF (CPART_OFF + NBLK)    // 256 per-sample-entropy partials
#define CEPART_OFF (HPART_OFF + NBLK)   // 256 codebook-entropy partials
#define CNT_OFF (CEPART_OFF + NBLK)     // completion counter (as unsigned)

// K1: fused sample + histogram. 256 blocks x 256 threads, 32 samples/block.
__global__ __launch_bounds__(256)
void lfq_fused_kernel(const float* __restrict__ x, float* __restrict__ out,
                      float* __restrict__ ws) {
    __shared__ float P[32 * 68];  // p[s][cb*16+d], stride 68 (4-aligned, bank-spread)
    __shared__ __align__(16) float T[64 * 128];  // [s*4+cb][128]: L(64) | H(64)
    __shared__ float CS[4], HS[4];

    const int t = threadIdx.x, w = t >> 6, lane = t & 63;
    const int blk = blockIdx.x;
    const int b0 = blk * SPB;

    if (blk == 0 && t == 0) *(unsigned*)(ws + CNT_OFF) = 0u;  // for K2

    // ---- phase 1: per-sample quantize chain, p-values, loss partials ----
    float csum = 0.f, hsum = 0.f;
    if (t < 192) {
        const int s = t & 31, dp = t >> 5;  // sample, dim-pair (2*dp, 2*dp+1)
        float2 xv = *(const float2*)(x + (b0 + s) * 12 + 2 * dp);
        float r0 = xv.x, r1 = xv.y;
        float xh0 = 0.f, xh1 = 0.f;
        const float scales[4] = {1.f, 0.5f, 0.25f, 0.125f};
#pragma unroll
        for (int cb = 0; cb < 4; ++cb) {
            const float sc = scales[cb];
            float q0 = (r0 > 0.f) ? sc : -sc;
            float q1 = (r1 > 0.f) ? sc : -sc;
            float d0 = r0 - q0, d1 = r1 - q1;
            csum += d0 * d0 + d1 * d1;
            // binary-softmax entropy: H2 = log(2cosh a) - a*tanh(a)
            float a0 = 2.f * sc * r0, a1 = 2.f * sc * r1;
            float m0 = fabsf(a0), m1 = fabsf(a1);
            float u0 = __expf(-2.f * m0), u1 = __expf(-2.f * m1);
            float i0 = __builtin_amdgcn_rcpf(1.f + u0);
            float i1 = __builtin_amdgcn_rcpf(1.f + u1);
            hsum += m0 + __logf(1.f + u0) - m0 * (1.f - u0) * i0;
            hsum += m1 + __logf(1.f + u1) - m1 * (1.f - u1) * i1;
            float pp0 = (a0 >= 0.f) ? i0 : u0 * i0;  // sigmoid(2a)
            float pp1 = (a1 >= 0.f) ? i1 : u1 * i1;
            *(float2*)(&P[s * 68 + cb * 16 + 2 * dp]) = make_float2(pp0, pp1);
            xh0 += q0;
            xh1 += q1;
            r0 = d0;
            r1 = d1;
        }
        *(float2*)(out + (b0 + s) * 12 + 2 * dp) = make_float2(xh0, xh1);
    }
#pragma unroll
    for (int off = 32; off; off >>= 1) {
        csum += __shfl_down(csum, off);
        hsum += __shfl_down(hsum, off);
    }
    if (lane == 0) {
        CS[w] = csum;
        HS[w] = hsum;
    }
    __syncthreads();
    if (t == 0) {
        ws[CPART_OFF + blk] = CS[0] + CS[1] + CS[2] + CS[3];
        ws[HPART_OFF + blk] = HS[0] + HS[1] + HS[2] + HS[3];
    }

    // ---- phases 2-3: table build + outer-product accumulate ----
    float acc[4][16];
#pragma unroll
    for (int cb = 0; cb < 4; ++cb)
#pragma unroll
        for (int i = 0; i < 16; ++i) acc[cb][i] = 0.f;

    const int lg = lane & 15, lh = lane >> 4;

    for (int round = 0; round < 2; ++round) {
        __syncthreads();  // T safe to overwrite; P ready (round 0)
        const int sbase = round * 16;
        // build: wave w handles cb=w for s=0..15; lane = table entry index
        for (int i = 0; i < 16; ++i) {
            const float* pp = &P[(sbase + i) * 68 + w * 16];
            float4 pA = *(const float4*)pp;        // p0..p3
            float4 pB = *(const float4*)(pp + 4);  // p4..p7
            float4 pC = *(const float4*)(pp + 8);  // p8..p11
            float L = (lane & 1) ? pA.x : 1.f - pA.x;
            L *= (lane & 2) ? pA.y : 1.f - pA.y;
            L *= (lane & 4) ? pA.z : 1.f - pA.z;
            L *= (lane & 8) ? pA.w : 1.f - pA.w;
            L *= (lane & 16) ? pB.x : 1.f - pB.x;
            L *= (lane & 32) ? pB.y : 1.f - pB.y;
            float H = (lane & 1) ? pB.z : 1.f - pB.z;
            H *= (lane & 2) ? pB.w : 1.f - pB.w;
            H *= (lane & 4) ? pC.x : 1.f - pC.x;
            H *= (lane & 8) ? pC.y : 1.f - pC.y;
            H *= (lane & 16) ? pC.z : 1.f - pC.z;
            H *= (lane & 32) ? pC.w : 1.f - pC.w;
            float* Trow = &T[(i * 4 + w) * 128];
            Trow[lane] = L;
            Trow[64 + lane] = H;
        }
        __syncthreads();
        // accumulate: thread owns hi in {16w+4*lh+0..3}, lo in {4*lg+0..3}
#pragma unroll 2
        for (int s = 0; s < 16; ++s) {
#pragma unroll
            for (int cb = 0; cb < 4; ++cb) {
                const float* Ts = &T[(s * 4 + cb) * 128];
                float4 L4 = *(const float4*)(Ts + 4 * lg);
                float4 H4 = *(const float4*)(Ts + 64 + 16 * w + 4 * lh);
                acc[cb][0] += H4.x * L4.x;
                acc[cb][1] += H4.x * L4.y;
                acc[cb][2] += H4.x * L4.z;
                acc[cb][3] += H4.x * L4.w;
                acc[cb][4] += H4.y * L4.x;
                acc[cb][5] += H4.y * L4.y;
                acc[cb][6] += H4.y * L4.z;
                acc[cb][7] += H4.y * L4.w;
                acc[cb][8] += H4.z * L4.x;
                acc[cb][9] += H4.z * L4.y;
                acc[cb][10] += H4.z * L4.z;
                acc[cb][11] += H4.z * L4.w;
                acc[cb][12] += H4.w * L4.x;
                acc[cb][13] += H4.w * L4.y;
                acc[cb][14] += H4.w * L4.z;
                acc[cb][15] += H4.w * L4.w;
            }
        }
    }
    float* mp = ws + PART_OFF + (size_t)blk * HBINS;
#pragma unroll
    for (int cb = 0; cb < 4; ++cb)
#pragma unroll
        for (int hh = 0; hh < 4; ++hh) {
            int hi = 16 * w + 4 * lh + hh;
            *(float4*)(mp + cb * NBINS + hi * 64 + 4 * lg) =
                make_float4(acc[cb][hh * 4 + 0], acc[cb][hh * 4 + 1],
                            acc[cb][hh * 4 + 2], acc[cb][hh * 4 + 3]);
        }
}

// K2: bin reduction + codebook-entropy term; last block finalizes scalars.
__global__ __launch_bounds__(256)
void lfq_reduce_kernel(const float* __restrict__ part, float* __restrict__ ws,
                       float* __restrict__ out) {
    const int t = threadIdx.x, w = t >> 6, lane = t & 63;
    const int bin = blockIdx.x * 64 + lane;
    const float* p = part + (size_t)(w * 64) * HBINS + bin;
    float s0 = 0.f, s1 = 0.f, s2 = 0.f, s3 = 0.f;
#pragma unroll 4
    for (int j = 0; j < 64; j += 4) {
        s0 += p[(size_t)(j + 0) * HBINS];
        s1 += p[(size_t)(j + 1) * HBINS];
        s2 += p[(size_t)(j + 2) * HBINS];
        s3 += p[(size_t)(j + 3) * HBINS];
    }
    __shared__ float S[4][64];
    S[w][lane] = s0 + s1 + s2 + s3;
    __syncthreads();
    if (w == 0) {
        float tot = S[0][lane] + S[1][lane] + S[2][lane] + S[3][lane];
        float avgp = tot * (1.f / 8192.f);
        float ce = avgp * __logf(avgp + 1e-9f);
#pragma unroll
        for (int off = 32; off; off >>= 1) ce += __shfl_down(ce, off);
        if (lane == 0) ws[CEPART_OFF + blockIdx.x] = ce;
    }
    __threadfence();  // release our ce partial to device scope
    __shared__ int lastFlag;
    if (t == 0) {
        unsigned old = atomicAdd((unsigned*)(ws + CNT_OFF), 1u);
        lastFlag = (old == NBLK - 1);
    }
    __syncthreads();
    if (lastFlag) {
        __threadfence();  // acquire all other blocks' partials
        float ce2 = ws[CEPART_OFF + t];
        float cs = ws[CPART_OFF + t];
        float hs = ws[HPART_OFF + t];
#pragma unroll
        for (int off = 32; off; off >>= 1) {
            ce2 += __shfl_down(ce2, off);
            cs += __shfl_down(cs, off);
            hs += __shfl_down(hs, off);
        }
        __shared__ float R[3][4];
        if (lane == 0) {
            R[0][w] = ce2;
            R[1][w] = cs;
            R[2][w] = hs;
        }
        __syncthreads();
        if (t == 0) {
            float cesum = R[0][0] + R[0][1] + R[0][2] + R[0][3];
            float commit = (R[1][0] + R[1][1] + R[1][2] + R[1][3]) *
                           (1.f / (8192.f * 12.f));
            float pse =
                (R[2][0] + R[2][1] + R[2][2] + R[2][3]) * (1.f / 8192.f);
            float codebook_entropy = -cesum;
            float entropy_loss = pse - codebook_entropy;
            float loss = 0.2f * commit + entropy_loss;
            out[BATCH * 12 + 0] = loss;
            out[BATCH * 12 + 1] = commit;
            out[BATCH * 12 + 2] = commit;  // codebook == commit in forward
            out[BATCH * 12 + 3] = entropy_loss;
        }
    }
}

extern "C" void kernel_launch(void* const* d_in, const int* in_sizes, int n_in,
                              void* d_out, int out_size, void* d_ws,
                              size_t ws_size, hipStream_t stream) {
    const float* x = (const float*)d_in[0];
    float* out = (float*)d_out;
    float* ws = (float*)d_ws;

    hipLaunchKernelGGL(lfq_fused_kernel, dim3(NBLK), dim3(256), 0, stream, x,
                       out, ws);
    hipLaunchKernelGGL(lfq_reduce_kernel, dim3(NBLK), dim3(256), 0, stream,
                       ws + PART_OFF, ws, out);
}

// Round 4
// 45.926 us; speedup vs baseline: 1.8059x; 1.0155x over previous
//
#include <hip/hip_runtime.h>
#include <math.h>

#define BATCH 8192
#define NCB 4
#define NBINS 4096
#define HBINS (NCB * NBINS)  // 16384
#define NBLK 256
#define SPB 32  // samples per block

// ws float offsets — every slot written each call before use; counter zeroed
// by K1 block 0 each call (poison-safe, deterministic).
#define PART_OFF 0                     // 256 * 16384 partial hists
#define CPART_OFF (NBLK * HBINS)       // commit partials (256)
#define HPART_OFF (CPART_OFF + NBLK)   // per-sample-entropy partials (256)
#define CEPART_OFF (HPART_OFF + NBLK)  // codebook-entropy partials (256)
#define CNT_OFF (CEPART_OFF + NBLK)    // completion counter (unsigned)

// K1: fused sample + histogram. 256 blocks x 256 threads, 32 samples/block.
// Wave w owns codebook cb=w; lane owns an 8x8 (hi x lo) bin tile.
__global__ __launch_bounds__(256)
void lfq_fused_kernel(const float* __restrict__ x, float* __restrict__ out,
                      float* __restrict__ ws) {
    __shared__ float P[32 * 68];  // p[s][cb*16+d], stride 68
    __shared__ __align__(16) float T[64 * 128];  // [i*4+w][128]: L(64)|H(64)
    __shared__ float CS[4], HS[4];

    const int t = threadIdx.x, w = t >> 6, lane = t & 63;
    const int blk = blockIdx.x, b0 = blk * SPB;

    if (blk == 0 && t == 0) *(unsigned*)(ws + CNT_OFF) = 0u;  // for K2

    // ---- phase 1: per-sample quantize chain, p-values, loss partials ----
    float csum = 0.f, hsum = 0.f;
    if (t < 192) {
        const int s = t & 31, dp = t >> 5;  // sample, dim-pair (2dp, 2dp+1)
        float2 xv = *(const float2*)(x + (b0 + s) * 12 + 2 * dp);
        float r0 = xv.x, r1 = xv.y;
        float xh0 = 0.f, xh1 = 0.f;
        const float scales[4] = {1.f, 0.5f, 0.25f, 0.125f};
#pragma unroll
        for (int cb = 0; cb < 4; ++cb) {
            const float sc = scales[cb];
            float q0 = (r0 > 0.f) ? sc : -sc;
            float q1 = (r1 > 0.f) ? sc : -sc;
            float d0 = r0 - q0, d1 = r1 - q1;
            csum += d0 * d0 + d1 * d1;
            // binary-softmax entropy: H2 = log(2cosh a) - a*tanh(a)
            float a0 = 2.f * sc * r0, a1 = 2.f * sc * r1;
            float m0 = fabsf(a0), m1 = fabsf(a1);
            float u0 = __expf(-2.f * m0), u1 = __expf(-2.f * m1);
            float i0 = __builtin_amdgcn_rcpf(1.f + u0);
            float i1 = __builtin_amdgcn_rcpf(1.f + u1);
            hsum += m0 + __logf(1.f + u0) - m0 * (1.f - u0) * i0;
            hsum += m1 + __logf(1.f + u1) - m1 * (1.f - u1) * i1;
            float pp0 = (a0 >= 0.f) ? i0 : u0 * i0;  // sigmoid(2a)
            float pp1 = (a1 >= 0.f) ? i1 : u1 * i1;
            *(float2*)(&P[s * 68 + cb * 16 + 2 * dp]) = make_float2(pp0, pp1);
            xh0 += q0;
            xh1 += q1;
            r0 = d0;
            r1 = d1;
        }
        *(float2*)(out + (b0 + s) * 12 + 2 * dp) = make_float2(xh0, xh1);
    }
#pragma unroll
    for (int off = 32; off; off >>= 1) {
        csum += __shfl_down(csum, off);
        hsum += __shfl_down(hsum, off);
    }
    if (lane == 0) {
        CS[w] = csum;
        HS[w] = hsum;
    }
    __syncthreads();  // P/CS/HS ready — the ONLY barrier in this kernel
    if (t == 0) {
        ws[CPART_OFF + blk] = CS[0] + CS[1] + CS[2] + CS[3];
        ws[HPART_OFF + blk] = HS[0] + HS[1] + HS[2] + HS[3];
    }

    // ---- phases 2-3: table build + 8x8 outer-product accumulate ----
    // T rows (i*4+w) are wave-private: built and read only by wave w.
    const int lo0 = 8 * (lane & 7), hi0 = 8 * (lane >> 3);
    float acc[8][8];
#pragma unroll
    for (int i = 0; i < 8; ++i)
#pragma unroll
        for (int j = 0; j < 8; ++j) acc[i][j] = 0.f;

    for (int round = 0; round < 2; ++round) {
        const int sbase = round * 16;
        // build: lane computes table entry `lane` of L and H for cb=w
        for (int i = 0; i < 16; ++i) {
            const float* pp = &P[(sbase + i) * 68 + w * 16];
            float4 pA = *(const float4*)pp;        // p0..p3
            float4 pB = *(const float4*)(pp + 4);  // p4..p7
            float4 pC = *(const float4*)(pp + 8);  // p8..p11
            float L = (lane & 1) ? pA.x : 1.f - pA.x;
            L *= (lane & 2) ? pA.y : 1.f - pA.y;
            L *= (lane & 4) ? pA.z : 1.f - pA.z;
            L *= (lane & 8) ? pA.w : 1.f - pA.w;
            L *= (lane & 16) ? pB.x : 1.f - pB.x;
            L *= (lane & 32) ? pB.y : 1.f - pB.y;
            float H = (lane & 1) ? pB.z : 1.f - pB.z;
            H *= (lane & 2) ? pB.w : 1.f - pB.w;
            H *= (lane & 4) ? pC.x : 1.f - pC.x;
            H *= (lane & 8) ? pC.y : 1.f - pC.y;
            H *= (lane & 16) ? pC.z : 1.f - pC.z;
            H *= (lane & 32) ? pC.w : 1.f - pC.w;
            float* Trow = &T[(i * 4 + w) * 128];
            Trow[lane] = L;
            Trow[64 + lane] = H;
        }
        // accumulate: 4 x ds_read_b128 per sample -> 64 FMAs
#pragma unroll 2
        for (int i = 0; i < 16; ++i) {
            const float* Ts = &T[(i * 4 + w) * 128];
            float4 La = *(const float4*)(Ts + lo0);
            float4 Lb = *(const float4*)(Ts + lo0 + 4);
            float4 Ha = *(const float4*)(Ts + 64 + hi0);
            float4 Hb = *(const float4*)(Ts + 64 + hi0 + 4);
            float Lv[8] = {La.x, La.y, La.z, La.w, Lb.x, Lb.y, Lb.z, Lb.w};
            float Hv[8] = {Ha.x, Ha.y, Ha.z, Ha.w, Hb.x, Hb.y, Hb.z, Hb.w};
#pragma unroll
            for (int ii = 0; ii < 8; ++ii)
#pragma unroll
                for (int jj = 0; jj < 8; ++jj)
                    acc[ii][jj] += Hv[ii] * Lv[jj];
        }
    }
    float* mp = ws + PART_OFF + (size_t)blk * HBINS + w * NBINS;
#pragma unroll
    for (int ii = 0; ii < 8; ++ii) {
        *(float4*)(mp + (hi0 + ii) * 64 + lo0) =
            make_float4(acc[ii][0], acc[ii][1], acc[ii][2], acc[ii][3]);
        *(float4*)(mp + (hi0 + ii) * 64 + lo0 + 4) =
            make_float4(acc[ii][4], acc[ii][5], acc[ii][6], acc[ii][7]);
    }
}

// K2: bin reduction + codebook-entropy term; last block finalizes scalars.
__global__ __launch_bounds__(256)
void lfq_reduce_kernel(const float* __restrict__ part, float* __restrict__ ws,
                       float* __restrict__ out) {
    const int t = threadIdx.x, w = t >> 6, lane = t & 63;
    const int bin = blockIdx.x * 64 + lane;
    const float* p = part + (size_t)(w * 64) * HBINS + bin;
    float s0 = 0.f, s1 = 0.f, s2 = 0.f, s3 = 0.f;
#pragma unroll 4
    for (int j = 0; j < 64; j += 4) {
        s0 += p[(size_t)(j + 0) * HBINS];
        s1 += p[(size_t)(j + 1) * HBINS];
        s2 += p[(size_t)(j + 2) * HBINS];
        s3 += p[(size_t)(j + 3) * HBINS];
    }
    __shared__ float S[4][64];
    S[w][lane] = s0 + s1 + s2 + s3;
    __syncthreads();
    if (w == 0) {
        float tot = S[0][lane] + S[1][lane] + S[2][lane] + S[3][lane];
        float avgp = tot * (1.f / 8192.f);
        float ce = avgp * __logf(avgp + 1e-9f);
#pragma unroll
        for (int off = 32; off; off >>= 1) ce += __shfl_down(ce, off);
        if (lane == 0) ws[CEPART_OFF + blockIdx.x] = ce;
    }
    __threadfence();  // release our ce partial to device scope
    __shared__ int lastFlag;
    if (t == 0) {
        unsigned old = atomicAdd((unsigned*)(ws + CNT_OFF), 1u);
        lastFlag = (old == NBLK - 1);
    }
    __syncthreads();
    if (lastFlag) {
        __threadfence();  // acquire all other blocks' partials
        float ce2 = ws[CEPART_OFF + t];
        float cs = ws[CPART_OFF + t];
        float hs = ws[HPART_OFF + t];
#pragma unroll
        for (int off = 32; off; off >>= 1) {
            ce2 += __shfl_down(ce2, off);
            cs += __shfl_down(cs, off);
            hs += __shfl_down(hs, off);
        }
        __shared__ float R[3][4];
        if (lane == 0) {
            R[0][w] = ce2;
            R[1][w] = cs;
            R[2][w] = hs;
        }
        __syncthreads();
        if (t == 0) {
            float cesum = R[0][0] + R[0][1] + R[0][2] + R[0][3];
            float commit = (R[1][0] + R[1][1] + R[1][2] + R[1][3]) *
                           (1.f / (8192.f * 12.f));
            float pse =
                (R[2][0] + R[2][1] + R[2][2] + R[2][3]) * (1.f / 8192.f);
            float codebook_entropy = -cesum;
            float entropy_loss = pse - codebook_entropy;
            float loss = 0.2f * commit + entropy_loss;
            out[BATCH * 12 + 0] = loss;
            out[BATCH * 12 + 1] = commit;
            out[BATCH * 12 + 2] = commit;  // codebook == commit in forward
            out[BATCH * 12 + 3] = entropy_loss;
        }
    }
}

extern "C" void kernel_launch(void* const* d_in, const int* in_sizes, int n_in,
                              void* d_out, int out_size, void* d_ws,
                              size_t ws_size, hipStream_t stream) {
    const float* x = (const float*)d_in[0];
    float* out = (float*)d_out;
    float* ws = (float*)d_ws;

    hipLaunchKernelGGL(lfq_fused_kernel, dim3(NBLK), dim3(256), 0, stream, x,
                       out, ws);
    hipLaunchKernelGGL(lfq_reduce_kernel, dim3(NBLK), dim3(256), 0, stream,
                       ws + PART_OFF, ws, out);
}